// Round 1
// baseline (13250.069 us; speedup 1.0000x reference)
//
#include <hip/hip_runtime.h>
#include <hip/hip_cooperative_groups.h>

namespace cg = cooperative_groups;

#define N_NODES   500
#define N_EDGE_IN 2000
#define N_EDGE_TT 2500
#define VD        1000
#define STEPS     100
#define HID       8

// ---------------------------------------------------------------------------
// Kernel A: GCN norm weights. deg counts dst occurrences + self loop.
// wnorm[e] = dis[src]*dis[dst] for e<2000; wnorm[2000+i] = dis[i]^2 (self loop)
// ---------------------------------------------------------------------------
__global__ void prep_edges(const int* __restrict__ ei, float* __restrict__ wnorm) {
    __shared__ float deg[N_NODES];
    __shared__ float dis[N_NODES];
    int tid = threadIdx.x;
    for (int i = tid; i < N_NODES; i += 256) deg[i] = 1.0f;   // self loop
    __syncthreads();
    for (int e = tid; e < N_EDGE_IN; e += 256)
        atomicAdd(&deg[ei[N_EDGE_IN + e]], 1.0f);
    __syncthreads();
    for (int i = tid; i < N_NODES; i += 256) dis[i] = 1.0f / sqrtf(deg[i]);
    __syncthreads();
    for (int e = tid; e < N_EDGE_IN; e += 256)
        wnorm[e] = dis[ei[e]] * dis[ei[N_EDGE_IN + e]];
    for (int i = tid; i < N_NODES; i += 256)
        wnorm[N_EDGE_IN + i] = dis[i] * dis[i];
}

// ---------------------------------------------------------------------------
// Kernel B: zA[t][j] = dot(z, A[t][j]) + b[t][j]   (100000 rows, parallel)
// one wave per row, float4 loads, z staged in LDS
// ---------------------------------------------------------------------------
__global__ __launch_bounds__(256) void za_kernel(const float* __restrict__ z,
                                                 const float* __restrict__ A,
                                                 const float* __restrict__ b,
                                                 float* __restrict__ zA) {
    __shared__ float4 zs[VD / 4];
    int tid = threadIdx.x;
    for (int i = tid; i < VD / 4; i += 256) zs[i] = ((const float4*)z)[i];
    __syncthreads();
    int wid = tid >> 6, lane = tid & 63;
    size_t row = (size_t)blockIdx.x * 4 + wid;
    if (row >= (size_t)STEPS * VD) return;
    const float4* Arow = (const float4*)(A + row * VD);
    float sum = 0.0f;
    for (int idx = lane; idx < VD / 4; idx += 64) {
        float4 a = Arow[idx]; float4 zz = zs[idx];
        sum += a.x * zz.x + a.y * zz.y + a.z * zz.z + a.w * zz.w;
    }
    for (int off = 32; off > 0; off >>= 1) sum += __shfl_down(sum, off, 64);
    if (lane == 0) zA[row] = sum + b[row];
}

// ---------------------------------------------------------------------------
// Kernel C: 100 sequential steps, cooperative.
//   block 0       : GNN (8 MixHop layers, LDS) -> u
//   blocks 1..250 : prefetch 4 rows of Bm[t] to LDS (overlaps GNN), then
//                   v_{t+1}[r] = dot(Bm[t][r], u) + zA[t][r]
// d_out layout: [0,1000) v_last ; [1000, 1000+101*1000) vs
// ---------------------------------------------------------------------------
__global__ __launch_bounds__(256) void step_kernel(
    const float* __restrict__ Bm, const float* __restrict__ W,
    const float* __restrict__ bW, const float* __restrict__ lng,
    const float* __restrict__ lnb, const int* __restrict__ ei,
    const float* __restrict__ zA, const float* __restrict__ wnorm,
    float* __restrict__ u, float* __restrict__ out)
{
    cg::grid_group grid = cg::this_grid();
    __shared__ float smem[4000];            // 16 KB: Bm stage / (X:1000, agg:1000)
    int tid = threadIdx.x;
    int bid = blockIdx.x;
    float* vs = out + VD;                   // vs[t] = vs + t*1000

    if (bid == 1) {                         // vs[0] = [0]*500 + [1]*500 (output only)
        for (int i = tid; i < VD; i += 256) vs[i] = (i < N_NODES) ? 0.0f : 1.0f;
    }

    for (int t = 0; t < STEPS; ++t) {
        if (bid == 0) {
            // ---------------- GNN on v_t ----------------
            float* X   = smem;              // X[i*2+c]
            float* agg = smem + 2 * N_NODES;
            const float* v = vs + (size_t)t * VD;
            if (t == 0) {
                for (int i = tid; i < N_NODES; i += 256) { X[2*i] = 0.0f; X[2*i+1] = 1.0f; }
            } else {
                for (int i = tid; i < N_NODES; i += 256) { X[2*i] = v[i]; X[2*i+1] = v[N_NODES + i]; }
            }
            __syncthreads();
            for (int l = 0; l < HID; ++l) {
                const float* Wl = W   + ((size_t)t * HID + l) * 8;
                const float* bl = bW  + ((size_t)t * HID + l) * 4;
                const float* g  = lng + ((size_t)t * HID + l) * 2;
                const float* be = lnb + ((size_t)t * HID + l) * 2;
                for (int i = tid; i < 2 * N_NODES; i += 256) agg[i] = 0.0f;
                __syncthreads();
                for (int e = tid; e < N_EDGE_TT; e += 256) {
                    int s, d; float wt = wnorm[e];
                    if (e < N_EDGE_IN) { s = ei[e]; d = ei[N_EDGE_IN + e]; }
                    else               { s = d = e - N_EDGE_IN; }
                    atomicAdd(&agg[2*d],     wt * X[2*s]);
                    atomicAdd(&agg[2*d + 1], wt * X[2*s + 1]);
                }
                __syncthreads();
                float w00 = Wl[0], w01 = Wl[1], w10 = Wl[2], w11 = Wl[3];
                float p00 = Wl[4], p01 = Wl[5], p10 = Wl[6], p11 = Wl[7];
                float c0 = bl[0] + bl[2], c1 = bl[1] + bl[3];
                float g0 = g[0], g1 = g[1], e0 = be[0], e1 = be[1];
                for (int i = tid; i < N_NODES; i += 256) {
                    float h0 = X[2*i], h1 = X[2*i+1];
                    float a0 = agg[2*i], a1 = agg[2*i+1];
                    float o0 = w00*h0 + w01*h1 + p00*a0 + p01*a1 + c0;
                    float o1 = w10*h0 + w11*h1 + p10*a0 + p11*a1 + c1;
                    float d0 = 0.5f * (o0 - o1);        // o0 - mean; (o1-mean) = -d0
                    float r  = 1.0f / sqrtf(d0*d0 + 1e-5f);
                    float n0 =  d0 * r * g0 + e0;
                    float n1 = -d0 * r * g1 + e1;
                    n0 = (n0 > 0.0f) ? n0 : 0.01f * n0;
                    n1 = (n1 > 0.0f) ? n1 : 0.01f * n1;
                    X[2*i] = n0; X[2*i+1] = n1;
                }
                __syncthreads();
            }
            for (int i = tid; i < N_NODES; i += 256) {
                u[i] = X[2*i]; u[N_NODES + i] = X[2*i + 1];
            }
            __threadfence();
        } else {
            // ---------------- prefetch Bm[t] rows into LDS (indep of u) -----
            const float4* src = (const float4*)(Bm + (size_t)t * VD * VD
                                                   + (size_t)(bid - 1) * 4 * VD);
            float4* dst4 = (float4*)smem;
            for (int i = tid; i < VD; i += 256) dst4[i] = src[i];
        }
        grid.sync();                        // u visible; Bm staged
        if (bid != 0) {
            int wid = tid >> 6, lane = tid & 63;
            int r = (bid - 1) * 4 + wid;
            const float4* brow = ((const float4*)smem) + wid * (VD / 4);
            const float4* u4 = (const float4*)u;
            float sum = 0.0f;
            for (int idx = lane; idx < VD / 4; idx += 64) {
                float4 bb = brow[idx]; float4 uu = u4[idx];
                sum += bb.x*uu.x + bb.y*uu.y + bb.z*uu.z + bb.w*uu.w;
            }
            for (int off = 32; off > 0; off >>= 1) sum += __shfl_down(sum, off, 64);
            if (lane == 0) {
                float val = sum + zA[(size_t)t * VD + r];
                vs[(size_t)(t + 1) * VD + r] = val;
                if (t == STEPS - 1) out[r] = val;   // v_last
            }
            __threadfence();
        }
        grid.sync();                        // v_{t+1} visible for next GNN
    }
}

// ---------------------------------------------------------------------------
extern "C" void kernel_launch(void* const* d_in, const int* in_sizes, int n_in,
                              void* d_out, int out_size, void* d_ws, size_t ws_size,
                              hipStream_t stream) {
    const float* z   = (const float*)d_in[0];
    const int*   ei  = (const int*)d_in[1];
    const float* A   = (const float*)d_in[2];
    const float* Bm  = (const float*)d_in[3];
    const float* b   = (const float*)d_in[4];
    const float* W   = (const float*)d_in[5];
    const float* bW  = (const float*)d_in[6];
    const float* lng = (const float*)d_in[7];
    const float* lnb = (const float*)d_in[8];
    float* out = (float*)d_out;

    char* ws = (char*)d_ws;
    float* zA    = (float*)ws;              // 100000 floats = 400000 B
    float* wnorm = (float*)(ws + 400000);   // 2500 floats
    float* ubuf  = (float*)(ws + 410000);   // 1000 floats

    prep_edges<<<dim3(1), dim3(256), 0, stream>>>(ei, wnorm);
    za_kernel<<<dim3(STEPS * VD / 4), dim3(256), 0, stream>>>(z, A, b, zA);

    void* args[] = { (void*)&Bm, (void*)&W, (void*)&bW, (void*)&lng, (void*)&lnb,
                     (void*)&ei, (void*)&zA, (void*)&wnorm, (void*)&ubuf, (void*)&out };
    hipLaunchCooperativeKernel((void*)step_kernel, dim3(251), dim3(256),
                               args, 0, stream);
}

// Round 2
// 6822.254 us; speedup vs baseline: 1.9422x; 1.9422x over previous
//
#include <hip/hip_runtime.h>

#define N_NODES   500
#define N_EDGE_IN 2000
#define N_EDGE_TT 2500
#define VD        1000
#define STEPS     100
#define HID       8
#define NBLK      63
#define TPB       1024

// ---------------------------------------------------------------------------
// Workspace layout (bytes):
//   zA    [0, 400000)          100000 floats
//   es    [400000, 410000)     2500 int
//   ed    [410000, 420000)     2500 int
//   ew    [420000, 430000)     2500 float
//   cnt   [430080]             barrier arrival counter
//   gen   [430208]             barrier generation
// ---------------------------------------------------------------------------

// Kernel A: GCN norm -> edge list (src, dst, weight) incl. self loops; init barrier.
__global__ void prep_edges(const int* __restrict__ ei, int* __restrict__ es,
                           int* __restrict__ ed, float* __restrict__ ew,
                           int* cnt, int* gen) {
    __shared__ float deg[N_NODES];
    __shared__ float dis[N_NODES];
    int tid = threadIdx.x;
    if (tid == 0) { *cnt = 0; *gen = 0; }
    for (int i = tid; i < N_NODES; i += 256) deg[i] = 1.0f;   // self loop
    __syncthreads();
    for (int e = tid; e < N_EDGE_IN; e += 256)
        atomicAdd(&deg[ei[N_EDGE_IN + e]], 1.0f);
    __syncthreads();
    for (int i = tid; i < N_NODES; i += 256) dis[i] = 1.0f / sqrtf(deg[i]);
    __syncthreads();
    for (int e = tid; e < N_EDGE_IN; e += 256) {
        int s = ei[e], d = ei[N_EDGE_IN + e];
        es[e] = s; ed[e] = d; ew[e] = dis[s] * dis[d];
    }
    for (int i = tid; i < N_NODES; i += 256) {
        es[N_EDGE_IN + i] = i; ed[N_EDGE_IN + i] = i; ew[N_EDGE_IN + i] = dis[i] * dis[i];
    }
}

// Kernel B: zA[t][j] = dot(z, A[t][j]) + b[t][j]  (fully parallel, HBM-bound)
__global__ __launch_bounds__(256) void za_kernel(const float* __restrict__ z,
                                                 const float* __restrict__ A,
                                                 const float* __restrict__ b,
                                                 float* __restrict__ zA) {
    __shared__ float4 zs[VD / 4];
    int tid = threadIdx.x;
    for (int i = tid; i < VD / 4; i += 256) zs[i] = ((const float4*)z)[i];
    __syncthreads();
    int wid = tid >> 6, lane = tid & 63;
    size_t row = (size_t)blockIdx.x * 4 + wid;
    if (row >= (size_t)STEPS * VD) return;
    const float4* Arow = (const float4*)(A + row * VD);
    float sum = 0.0f;
    for (int idx = lane; idx < VD / 4; idx += 64) {
        float4 a = Arow[idx]; float4 zz = zs[idx];
        sum += a.x * zz.x + a.y * zz.y + a.z * zz.z + a.w * zz.w;
    }
    for (int off = 32; off > 0; off >>= 1) sum += __shfl_down(sum, off, 64);
    if (lane == 0) zA[row] = sum + b[row];
}

// ---------------------------------------------------------------------------
// Kernel C: 100 sequential steps. 63 blocks x 1024 threads, cooperative.
// Every block computes the GNN redundantly in its own LDS (no producer wait);
// each of its 16 waves owns one row of Bm[t] prefetched into 16 VGPRs/lane.
// One custom grid barrier per step.
// ---------------------------------------------------------------------------
__global__ __launch_bounds__(TPB) void step_kernel(
    const float* __restrict__ Bm, const float* __restrict__ W,
    const float* __restrict__ bW, const float* __restrict__ lng,
    const float* __restrict__ lnb, const float* __restrict__ zA,
    const int* __restrict__ esg, const int* __restrict__ edg,
    const float* __restrict__ ewg, int* cnt, int* gen, float* __restrict__ out)
{
    __shared__ float X[2 * N_NODES];
    __shared__ float agg[2 * N_NODES];
    __shared__ __align__(16) float uL[1024];
    __shared__ float pw[HID * 16];
    __shared__ int   esh[N_EDGE_TT];
    __shared__ int   edh[N_EDGE_TT];
    __shared__ float ewh[N_EDGE_TT];

    const int tid  = threadIdx.x;
    const int bid  = blockIdx.x;
    const int wid  = tid >> 6;
    const int lane = tid & 63;
    const int r    = bid * 16 + wid;        // output row owned by this wave
    float* vs = out + VD;                   // vs[t] = vs + t*1000
    int mygen = 0;

    for (int e = tid; e < N_EDGE_TT; e += TPB) { esh[e] = esg[e]; edh[e] = edg[e]; ewh[e] = ewg[e]; }
    if (tid >= 1000) uL[tid] = 0.0f;        // pad (never rewritten)
    if (bid == 0 && tid < VD) vs[tid] = (tid < N_NODES) ? 0.0f : 1.0f;  // vs[0], output-only

    for (int t = 0; t < STEPS; ++t) {
        // ---- per-step GNN params -> LDS (small, L2-hot) ----
        if (tid < HID * 16) {
            int l = tid >> 4, k = tid & 15;
            size_t base = (size_t)t * HID + l;
            float v;
            if      (k < 8)  v = W  [base * 8 + k];
            else if (k < 12) v = bW [base * 4 + (k - 8)];
            else if (k < 14) v = lng[base * 2 + (k - 12)];
            else             v = lnb[base * 2 + (k - 14)];
            pw[l * 16 + k] = v;
        }
        // ---- prefetch Bm[t] row r into registers (indep of u; overlaps GNN) ----
        float4 breg[4];
        {
            const float4* row4 = (const float4*)(Bm + ((size_t)t * VD + (r < VD ? r : 0)) * VD);
            #pragma unroll
            for (int j = 0; j < 4; ++j) {
                int e = j * 256 + lane * 4;
                breg[j] = (r < VD && e < VD) ? row4[j * 64 + lane]
                                             : make_float4(0.f, 0.f, 0.f, 0.f);
            }
        }
        float za_r = (r < VD) ? zA[(size_t)t * VD + r] : 0.0f;

        // ---- load v_t -> X (interleaved channels) ----
        if (t == 0) {
            if (tid < N_NODES) { X[2*tid] = 0.0f; X[2*tid + 1] = 1.0f; }
        } else {
            const float* v = vs + (size_t)t * VD;
            if (tid < N_NODES) { X[2*tid] = v[tid]; X[2*tid + 1] = v[N_NODES + tid]; }
        }
        __syncthreads();

        // ---- 8 MixHop layers, all in LDS ----
        for (int l = 0; l < HID; ++l) {
            if (tid < 2 * N_NODES) agg[tid] = 0.0f;
            __syncthreads();
            #pragma unroll
            for (int eb = 0; eb < 3; ++eb) {
                int e = eb * TPB + tid;
                if (e < N_EDGE_TT) {
                    int s = esh[e], d = edh[e]; float wt = ewh[e];
                    atomicAdd(&agg[2*d],     wt * X[2*s]);
                    atomicAdd(&agg[2*d + 1], wt * X[2*s + 1]);
                }
            }
            __syncthreads();
            if (tid < N_NODES) {
                const float* P = pw + l * 16;
                float h0 = X[2*tid], h1 = X[2*tid+1], a0 = agg[2*tid], a1 = agg[2*tid+1];
                float o0 = P[0]*h0 + P[1]*h1 + P[4]*a0 + P[5]*a1 + P[8] + P[10];
                float o1 = P[2]*h0 + P[3]*h1 + P[6]*a0 + P[7]*a1 + P[9] + P[11];
                float d0 = 0.5f * (o0 - o1);
                float rr = 1.0f / sqrtf(d0*d0 + 1e-5f);
                float n0 =  d0 * rr * P[12] + P[14];
                float n1 = -d0 * rr * P[13] + P[15];
                X[2*tid]     = (n0 > 0.0f) ? n0 : 0.01f * n0;
                X[2*tid + 1] = (n1 > 0.0f) ? n1 : 0.01f * n1;
            }
            __syncthreads();
        }

        // ---- linearize u ----
        if (tid < N_NODES) { uL[tid] = X[2*tid]; uL[N_NODES + tid] = X[2*tid + 1]; }
        __syncthreads();

        // ---- v_{t+1}[r] = Bm[t][r] . u + zA[t][r] ----
        if (r < VD) {
            const float4* u4 = (const float4*)uL;
            float sum = 0.0f;
            #pragma unroll
            for (int j = 0; j < 4; ++j) {
                float4 bb = breg[j]; float4 uu = u4[j * 64 + lane];
                sum += bb.x*uu.x + bb.y*uu.y + bb.z*uu.z + bb.w*uu.w;
            }
            #pragma unroll
            for (int off = 32; off > 0; off >>= 1) sum += __shfl_down(sum, off, 64);
            if (lane == 0) {
                float val = sum + za_r;
                vs[(size_t)(t + 1) * VD + r] = val;
                if (t == STEPS - 1) out[r] = val;
            }
        }

        // ---- one grid barrier per step ----
        __syncthreads();
        if (tid == 0) {
            __threadfence();                 // wb L2 (publish vs rows cross-XCD)
            int arrived = __hip_atomic_fetch_add(cnt, 1, __ATOMIC_ACQ_REL,
                                                 __HIP_MEMORY_SCOPE_AGENT);
            if (arrived == NBLK - 1) {
                __hip_atomic_store(cnt, 0, __ATOMIC_RELAXED, __HIP_MEMORY_SCOPE_AGENT);
                __hip_atomic_fetch_add(gen, 1, __ATOMIC_RELEASE, __HIP_MEMORY_SCOPE_AGENT);
            } else {
                while (__hip_atomic_load(gen, __ATOMIC_RELAXED,
                                         __HIP_MEMORY_SCOPE_AGENT) <= mygen)
                    __builtin_amdgcn_s_sleep(2);
            }
            mygen++;
            __threadfence();                 // inv L1/L2 before re-reading vs
        }
        __syncthreads();
    }
}

// ---------------------------------------------------------------------------
extern "C" void kernel_launch(void* const* d_in, const int* in_sizes, int n_in,
                              void* d_out, int out_size, void* d_ws, size_t ws_size,
                              hipStream_t stream) {
    const float* z   = (const float*)d_in[0];
    const int*   ei  = (const int*)d_in[1];
    const float* A   = (const float*)d_in[2];
    const float* Bm  = (const float*)d_in[3];
    const float* b   = (const float*)d_in[4];
    const float* W   = (const float*)d_in[5];
    const float* bW  = (const float*)d_in[6];
    const float* lng = (const float*)d_in[7];
    const float* lnb = (const float*)d_in[8];
    float* out = (float*)d_out;

    char* ws = (char*)d_ws;
    float* zA  = (float*)ws;
    int*   es  = (int*)  (ws + 400000);
    int*   ed  = (int*)  (ws + 410000);
    float* ew  = (float*)(ws + 420000);
    int*   cnt = (int*)  (ws + 430080);
    int*   gen = (int*)  (ws + 430208);

    prep_edges<<<dim3(1), dim3(256), 0, stream>>>(ei, es, ed, ew, cnt, gen);
    za_kernel<<<dim3(STEPS * VD / 4), dim3(256), 0, stream>>>(z, A, b, zA);

    void* args[] = { (void*)&Bm, (void*)&W, (void*)&bW, (void*)&lng, (void*)&lnb,
                     (void*)&zA, (void*)&es, (void*)&ed, (void*)&ew,
                     (void*)&cnt, (void*)&gen, (void*)&out };
    hipLaunchCooperativeKernel((void*)step_kernel, dim3(NBLK), dim3(TPB),
                               args, 0, stream);
}